// Round 1
// baseline (96.908 us; speedup 1.0000x reference)
//
#include <hip/hip_runtime.h>

// WideAndDeep forward, MI355X.
// Key insight: the network is fully linear (no activations), so
//   y[i] = dot(emb[x[i]], v) + c + Wo[0, F2 + x[i]]
// where v = W1^T @ (W2^T @ Wo_deep^T)  (128 floats) and
//       c = Wo_deep . (W2 @ b1 + b2) + bo  (scalar).
// Each block computes v/c redundantly (cheap, L1/L2-resident weights), then
// does the gather-dot for 32 rows (8 lanes per row, float4 loads).

#define DD 128
#define FF1 64
#define FF2 32

__global__ __launch_bounds__(256, 4) void wd_kernel(
    const int* __restrict__ x,
    const float* __restrict__ emb,
    const float* __restrict__ W1,
    const float* __restrict__ b1,
    const float* __restrict__ W2,
    const float* __restrict__ b2,
    const float* __restrict__ Wo,
    const float* __restrict__ bo,
    float* __restrict__ out,
    int B)
{
    __shared__ float t_s[FF1];            // t[f1] = sum_f2 Wo[f2] * W2[f2][f1]
    __shared__ float u_s[FF2];            // u[f2] = (W2[f2].b1 + b2[f2]) * Wo[f2]
    __shared__ __align__(16) float v_s[DD];
    __shared__ float c_s;

    const int tid = threadIdx.x;

    // ---- Phase 1: collapse the linear deep path (per block, tiny) ----
    if (tid < FF1) {
        float acc = 0.f;
        #pragma unroll
        for (int f2 = 0; f2 < FF2; ++f2)
            acc = fmaf(Wo[f2], W2[f2 * FF1 + tid], acc);
        t_s[tid] = acc;
    } else if (tid < FF1 + FF2) {
        const int f2 = tid - FF1;
        float acc = b2[f2];
        #pragma unroll
        for (int f1 = 0; f1 < FF1; ++f1)
            acc = fmaf(W2[f2 * FF1 + f1], b1[f1], acc);
        u_s[f2] = acc * Wo[f2];
    }
    __syncthreads();
    if (tid < DD) {
        float acc = 0.f;
        #pragma unroll
        for (int f1 = 0; f1 < FF1; ++f1)
            acc = fmaf(t_s[f1], W1[f1 * DD + tid], acc);   // coalesced row reads of W1
        v_s[tid] = acc;
    }
    if (tid == 0) {
        float acc = bo[0];
        #pragma unroll
        for (int f2 = 0; f2 < FF2; ++f2) acc += u_s[f2];
        c_s = acc;
    }
    __syncthreads();

    // ---- Phase 2: gather-dot, 8 lanes per row, 32 rows per block ----
    const int j   = tid & 7;    // lane within row-group
    const int grp = tid >> 3;   // row-group within block

    // v fragment for this lane: d = chunk*32 + j*4 .. +3  (banks j*4..j*4+3, conflict-free)
    const float4 vv0 = *(const float4*)&v_s[ 0 + j * 4];
    const float4 vv1 = *(const float4*)&v_s[32 + j * 4];
    const float4 vv2 = *(const float4*)&v_s[64 + j * 4];
    const float4 vv3 = *(const float4*)&v_s[96 + j * 4];
    const float cc = c_s;

    const int r = blockIdx.x * 32 + grp;
    if (r < B) {
        const int idx = x[r];
        const float4* __restrict__ ep = (const float4*)(emb + (size_t)idx * DD);
        const float wide = Wo[FF2 + idx];   // wide one-hot column

        // 4 independent 16B loads/lane; lanes j=0..7 cover 128B contiguous each
        const float4 e0 = ep[ 0 + j];
        const float4 e1 = ep[ 8 + j];
        const float4 e2 = ep[16 + j];
        const float4 e3 = ep[24 + j];

        float acc;
        acc = e0.x * vv0.x;
        acc = fmaf(e0.y, vv0.y, acc);
        acc = fmaf(e0.z, vv0.z, acc);
        acc = fmaf(e0.w, vv0.w, acc);
        acc = fmaf(e1.x, vv1.x, acc);
        acc = fmaf(e1.y, vv1.y, acc);
        acc = fmaf(e1.z, vv1.z, acc);
        acc = fmaf(e1.w, vv1.w, acc);
        acc = fmaf(e2.x, vv2.x, acc);
        acc = fmaf(e2.y, vv2.y, acc);
        acc = fmaf(e2.z, vv2.z, acc);
        acc = fmaf(e2.w, vv2.w, acc);
        acc = fmaf(e3.x, vv3.x, acc);
        acc = fmaf(e3.y, vv3.y, acc);
        acc = fmaf(e3.z, vv3.z, acc);
        acc = fmaf(e3.w, vv3.w, acc);

        // reduce across the 8 lanes of this row-group
        acc += __shfl_xor(acc, 1);
        acc += __shfl_xor(acc, 2);
        acc += __shfl_xor(acc, 4);

        if (j == 0) out[r] = acc + cc + wide;
    }
}

extern "C" void kernel_launch(void* const* d_in, const int* in_sizes, int n_in,
                              void* d_out, int out_size, void* d_ws, size_t ws_size,
                              hipStream_t stream) {
    const int*   x   = (const int*)  d_in[0];
    const float* emb = (const float*)d_in[1];
    const float* W1  = (const float*)d_in[2];
    const float* b1  = (const float*)d_in[3];
    const float* W2  = (const float*)d_in[4];
    const float* b2  = (const float*)d_in[5];
    const float* Wo  = (const float*)d_in[6];
    const float* bo  = (const float*)d_in[7];
    float* out = (float*)d_out;

    const int B = in_sizes[0];                 // 16384
    const int grid = (B + 31) / 32;            // 32 rows per block
    hipLaunchKernelGGL(wd_kernel, dim3(grid), dim3(256), 0, stream,
                       x, emb, W1, b1, W2, b2, Wo, bo, out, B);
}

// Round 2
// 96.757 us; speedup vs baseline: 1.0016x; 1.0016x over previous
//
#include <hip/hip_runtime.h>

// WideAndDeep forward, MI355X.
// The network is fully linear (no activations), so
//   y[i] = dot(emb[x[i]], v) + c + Wo[0, F2 + x[i]]
// where v = W1^T @ (W2^T @ Wo_deep^T) (128 floats), c = Wo_deep.(W2@b1+b2)+bo.
// Each block computes v/c redundantly (weights are L2-resident), overlapped
// with the emb-row gather loads which are issued at kernel entry.

#define DD  128
#define FF1 64
#define FF2 32
#define ROWS 16   // rows per block, 16 lanes per row

__global__ __launch_bounds__(256, 4) void wd_kernel(
    const int* __restrict__ x,
    const float* __restrict__ emb,
    const float* __restrict__ W1,
    const float* __restrict__ b1,
    const float* __restrict__ W2,
    const float* __restrict__ b2,
    const float* __restrict__ Wo,
    const float* __restrict__ bo,
    float* __restrict__ out,
    int B)
{
    __shared__ float t_s[FF1];            // t[f1] = sum_f2 Wo[f2] * W2[f2][f1]
    __shared__ float u_s[FF2];            // u[f2] = (W2[f2].b1 + b2[f2]) * Wo[f2]
    __shared__ __align__(16) float v_s[DD];
    __shared__ float c_s;

    const int tid = threadIdx.x;
    const int j   = tid & 15;             // lane within row-group
    const int grp = tid >> 4;             // row-group within block

    // ---- Issue the gather loads FIRST (independent of phase 1) ----
    // Their ~900-cycle HBM latency overlaps the linear-collapse compute below.
    const int r  = blockIdx.x * ROWS + grp;
    const int rc = (r < B) ? r : (B - 1);
    const int idx = x[rc];
    const float4* __restrict__ ep = (const float4*)(emb + (size_t)idx * DD);
    const float4 e0 = ep[ 0 + j];         // 16 lanes cover 256B contiguous
    const float4 e1 = ep[16 + j];
    const float wide = Wo[FF2 + idx];     // wide one-hot column

    // ---- Phase 1: collapse the linear deep path (per block, tiny) ----
    if (tid < FF1) {
        float acc = 0.f;
        #pragma unroll
        for (int f2 = 0; f2 < FF2; ++f2)
            acc = fmaf(Wo[f2], W2[f2 * FF1 + tid], acc);
        t_s[tid] = acc;
    } else if (tid < FF1 + FF2) {
        const int f2 = tid - FF1;
        float acc = b2[f2];
        #pragma unroll
        for (int f1 = 0; f1 < FF1; ++f1)
            acc = fmaf(W2[f2 * FF1 + f1], b1[f1], acc);
        u_s[f2] = acc * Wo[f2];
    }
    __syncthreads();
    if (tid < DD) {
        float acc = 0.f;
        #pragma unroll
        for (int f1 = 0; f1 < FF1; ++f1)
            acc = fmaf(t_s[f1], W1[f1 * DD + tid], acc);   // coalesced W1 rows
        v_s[tid] = acc;
    }
    if (tid == 0) {
        float acc = bo[0];
        #pragma unroll
        for (int f2 = 0; f2 < FF2; ++f2) acc += u_s[f2];
        c_s = acc;
    }
    __syncthreads();

    // ---- Phase 2: dot(e, v) — v frag reads are 2-way LDS aliasing (free) ----
    const float4 vv0 = *(const float4*)&v_s[ 0 + j * 4];
    const float4 vv1 = *(const float4*)&v_s[64 + j * 4];
    const float cc = c_s;

    float acc;
    acc = e0.x * vv0.x;
    acc = fmaf(e0.y, vv0.y, acc);
    acc = fmaf(e0.z, vv0.z, acc);
    acc = fmaf(e0.w, vv0.w, acc);
    acc = fmaf(e1.x, vv1.x, acc);
    acc = fmaf(e1.y, vv1.y, acc);
    acc = fmaf(e1.z, vv1.z, acc);
    acc = fmaf(e1.w, vv1.w, acc);

    // reduce across the 16 lanes of this row-group
    acc += __shfl_xor(acc, 1);
    acc += __shfl_xor(acc, 2);
    acc += __shfl_xor(acc, 4);
    acc += __shfl_xor(acc, 8);

    if (j == 0 && r < B) out[r] = acc + cc + wide;
}

extern "C" void kernel_launch(void* const* d_in, const int* in_sizes, int n_in,
                              void* d_out, int out_size, void* d_ws, size_t ws_size,
                              hipStream_t stream) {
    const int*   x   = (const int*)  d_in[0];
    const float* emb = (const float*)d_in[1];
    const float* W1  = (const float*)d_in[2];
    const float* b1  = (const float*)d_in[3];
    const float* W2  = (const float*)d_in[4];
    const float* b2  = (const float*)d_in[5];
    const float* Wo  = (const float*)d_in[6];
    const float* bo  = (const float*)d_in[7];
    float* out = (float*)d_out;

    const int B = in_sizes[0];                 // 16384
    const int grid = (B + ROWS - 1) / ROWS;    // 1024 blocks -> 4 blocks/CU
    hipLaunchKernelGGL(wd_kernel, dim3(grid), dim3(256), 0, stream,
                       x, emb, W1, b1, W2, b2, Wo, bo, out, B);
}